// Round 3
// baseline (8418.641 us; speedup 1.0000x reference)
//
#include <hip/hip_runtime.h>
#include <hip/hip_bf16.h>

using bf16 = __hip_bfloat16;

constexpr int B = 4, S = 4096, D = 1024, H = 16, DH = 64, WIN = 512, NW = S / WIN;
constexpr int M_ROWS = B * S;     // 16384
constexpr int CHUNK = 2048;       // FFN row chunk
constexpr int NCH = M_ROWS / CHUNK;

#define DEV static __device__ __forceinline__

DEV float bf2f(bf16 x) { return __bfloat162float(x); }

// 8 x bf16 (16B) -> 8 x f32
DEV void load8_f(const bf16* p, float* dst) {
    const uint4 u = *reinterpret_cast<const uint4*>(p);
    const unsigned w[4] = {u.x, u.y, u.z, u.w};
#pragma unroll
    for (int i = 0; i < 4; ++i) {
        dst[2 * i]     = __uint_as_float(w[i] << 16);
        dst[2 * i + 1] = __uint_as_float(w[i] & 0xffff0000u);
    }
}
// 8 x f32 (32B) -> 8 x f32
DEV void load8_f(const float* p, float* dst) {
    const float4 a = *reinterpret_cast<const float4*>(p);
    const float4 b = *reinterpret_cast<const float4*>(p + 4);
    dst[0] = a.x; dst[1] = a.y; dst[2] = a.z; dst[3] = a.w;
    dst[4] = b.x; dst[5] = b.y; dst[6] = b.z; dst[7] = b.w;
}

DEV unsigned pack2bf(float a, float b) {
    union { __hip_bfloat162 h2; unsigned u; } cv;
    cv.h2.x = __float2bfloat16(a);
    cv.h2.y = __float2bfloat16(b);
    return cv.u;
}

DEV void store_val(float* p, float v) { *p = v; }
DEV void store_val(bf16* p, float v) { *p = __float2bfloat16(v); }

// ---------------------------------------------------------------------------
// Tiled GEMM: out[m,n] = act( sum_k A[m,k]*W[n,k] + bias[n] ) [+ resid[m,n]]
// A: [M,K] (f32 or bf16), W: [N,K] f32, bias f32, resid bf16.
// BM=BN=64, BK=32, 256 threads, 4x4 microtile, fp32 accum. VALU version —
// MFMA conversion is next round; this round establishes a correct baseline.
// ---------------------------------------------------------------------------
template <typename TA, typename TO, bool RELU, bool RESID>
__global__ __launch_bounds__(256) void gemm_kernel(
    const TA* __restrict__ A, const float* __restrict__ Wt,
    const float* __restrict__ bias, const bf16* __restrict__ resid,
    TO* __restrict__ out, int K, int N) {
    constexpr int BM = 64, BK = 32;
    constexpr int LDP = BM + 4;  // pad keeps 16B alignment for float4 LDS reads
    __shared__ float As[BK][LDP];
    __shared__ float Bs[BK][LDP];

    const int tid = threadIdx.x;
    const int tm = tid >> 4;        // 0..15
    const int tn = tid & 15;        // 0..15
    const long blockM = (long)blockIdx.y * BM;
    const long blockN = (long)blockIdx.x * BM;
    const int lr = tid >> 2;        // 0..63: tile row this thread stages
    const int lk = (tid & 3) * 8;   // 0,8,16,24: k offset

    float acc[4][4] = {};
    const TA*   aptr = A  + (blockM + lr) * (long)K + lk;
    const float* bptr = Wt + (blockN + lr) * (long)K + lk;

    for (int k0 = 0; k0 < K; k0 += BK) {
        float ta[8], tb[8];
        load8_f(aptr + k0, ta);
        load8_f(bptr + k0, tb);
        __syncthreads();  // previous iteration's LDS reads done
#pragma unroll
        for (int i = 0; i < 8; ++i) {
            As[lk + i][lr] = ta[i];
            Bs[lk + i][lr] = tb[i];
        }
        __syncthreads();
#pragma unroll
        for (int kk = 0; kk < BK; ++kk) {
            const float4 av = *reinterpret_cast<const float4*>(&As[kk][tm * 4]);
            const float4 bv = *reinterpret_cast<const float4*>(&Bs[kk][tn * 4]);
            const float a[4] = {av.x, av.y, av.z, av.w};
            const float b[4] = {bv.x, bv.y, bv.z, bv.w};
#pragma unroll
            for (int i = 0; i < 4; ++i)
#pragma unroll
                for (int j = 0; j < 4; ++j) acc[i][j] = fmaf(a[i], b[j], acc[i][j]);
        }
    }

#pragma unroll
    for (int i = 0; i < 4; ++i) {
        const long m = blockM + tm * 4 + i;
#pragma unroll
        for (int j = 0; j < 4; ++j) {
            const long n = blockN + tn * 4 + j;
            float val = acc[i][j] + bias[n];
            if (RELU) val = fmaxf(val, 0.f);
            if (RESID) val += bf2f(resid[m * (long)N + n]);
            store_val(out + m * (long)N + n, val);
        }
    }
}

// ---------------------------------------------------------------------------
// Local causal attention, window=512, look_backward=1. Q/K/V bf16 in
// [B,S,H*DH] layout (head slice stride 1024). One thread per query row;
// fixed-max softmax (scores O(+-5): exp(s-16) cannot over/underflow in f32).
// "attn + attn" folded into 2/l. Output (bf16) OVERWRITES Q in place: each
// block writes exactly the (b,s,h) slices only it reads — race-free.
// ---------------------------------------------------------------------------
__global__ __launch_bounds__(256) void attn_kernel(
    bf16* __restrict__ q, const bf16* __restrict__ k,
    const bf16* __restrict__ v) {
    const int bid = blockIdx.x;               // ((b*H+h)*NW + wi)*2 + half
    const int half = bid & 1;
    const int wi = (bid >> 1) & (NW - 1);
    const int bh = bid >> 4;                  // b*H + h
    const int b_ = bh >> 4, h_ = bh & 15;
    const int qi = half * 256 + threadIdx.x;  // 0..511 within window
    const int qpos = wi * WIN + qi;

    bf16* qrow = q + ((long)b_ * S + qpos) * D + h_ * DH;
    float qf[64];
#pragma unroll
    for (int e8 = 0; e8 < 8; ++e8) load8_f(qrow + e8 * 8, qf + e8 * 8);
#pragma unroll
    for (int e = 0; e < 64; ++e) qf[e] *= 0.125f;  // d^-0.5

    const int jstart = (wi == 0) ? WIN : 0;  // k_pos >= 0
    const int jend = WIN + qi;               // k_pos <= q_pos
    const long kvbase = ((long)b_ * S + (long)(wi - 1) * WIN) * D + h_ * DH;

    float l = 0.f;
    float acc[64] = {};
    for (int j = jstart; j <= jend; ++j) {
        const long off = kvbase + (long)j * D;
        float s = 0.f;
#pragma unroll
        for (int e8 = 0; e8 < 8; ++e8) {
            float kf[8];
            load8_f(k + off + e8 * 8, kf);
#pragma unroll
            for (int i = 0; i < 8; ++i) s = fmaf(qf[e8 * 8 + i], kf[i], s);
        }
        const float p = __expf(s - 16.f);
        l += p;
#pragma unroll
        for (int e8 = 0; e8 < 8; ++e8) {
            float vf[8];
            load8_f(v + off + e8 * 8, vf);
#pragma unroll
            for (int i = 0; i < 8; ++i) acc[e8 * 8 + i] = fmaf(p, vf[i], acc[e8 * 8 + i]);
        }
    }
    const float inv = 2.f / l;  // x2 = "attn + attn"
    unsigned pk[32];
#pragma unroll
    for (int e = 0; e < 32; ++e)
        pk[e] = pack2bf(acc[2 * e] * inv, acc[2 * e + 1] * inv);
    uint4* op = reinterpret_cast<uint4*>(qrow);
#pragma unroll
    for (int e4 = 0; e4 < 8; ++e4)
        op[e4] = make_uint4(pk[4 * e4], pk[4 * e4 + 1], pk[4 * e4 + 2], pk[4 * e4 + 3]);
}

// ---------------------------------------------------------------------------
// LayerNorm over last dim (1024). One 256-thread block per row; biased var.
// g/be are f32. In-place safe: regs first, write after.
// ---------------------------------------------------------------------------
template <typename TI, typename TO>
__global__ __launch_bounds__(256) void ln_kernel(
    const TI* in, const float* __restrict__ g, const float* __restrict__ be,
    TO* out) {
    __shared__ float red[4];
    const long row = blockIdx.x;
    const TI* x = in + row * D;
    const int tid = threadIdx.x;

    float v[4];
    float s = 0.f;
#pragma unroll
    for (int i = 0; i < 4; ++i) {
        v[i] = (float)x[tid + i * 256];
        s += v[i];
    }
#pragma unroll
    for (int off = 32; off; off >>= 1) s += __shfl_down(s, off, 64);
    if ((tid & 63) == 0) red[tid >> 6] = s;
    __syncthreads();
    const float mu = (red[0] + red[1] + red[2] + red[3]) * (1.f / D);
    __syncthreads();

    float vs = 0.f;
#pragma unroll
    for (int i = 0; i < 4; ++i) {
        const float d0 = v[i] - mu;
        vs += d0 * d0;
    }
#pragma unroll
    for (int off = 32; off; off >>= 1) vs += __shfl_down(vs, off, 64);
    if ((tid & 63) == 0) red[tid >> 6] = vs;
    __syncthreads();
    const float inv = rsqrtf((red[0] + red[1] + red[2] + red[3]) * (1.f / D) + 1e-5f);

#pragma unroll
    for (int i = 0; i < 4; ++i) {
        const int c = tid + i * 256;
        store_val(out + row * D + c, (v[i] - mu) * inv * g[c] + be[c]);
    }
}

// ---------------------------------------------------------------------------
extern "C" void kernel_launch(void* const* d_in, const int* in_sizes, int n_in,
                              void* d_out, int out_size, void* d_ws, size_t ws_size,
                              hipStream_t stream) {
    // ALL inputs are float32 (reference setup_inputs uses jnp.float32).
    const float* src = (const float*)d_in[0];
    const float* wq = (const float*)d_in[1];  const float* bq = (const float*)d_in[2];
    const float* wk = (const float*)d_in[3];  const float* bk = (const float*)d_in[4];
    const float* wv = (const float*)d_in[5];  const float* bv = (const float*)d_in[6];
    const float* w1 = (const float*)d_in[7];  const float* b1 = (const float*)d_in[8];
    const float* w2 = (const float*)d_in[9];  const float* b2 = (const float*)d_in[10];
    const float* g1 = (const float*)d_in[11]; const float* be1 = (const float*)d_in[12];
    const float* g2 = (const float*)d_in[13]; const float* be2 = (const float*)d_in[14];

    // Workspace (peak 64 MiB):
    //   qb: ws + 0      bf16 [B,S,D]  32 MiB  (Q -> overwritten by 2*attn -> LN1'd x)
    //   kb: ws + 32MiB  bf16 [B,S,D]  32 MiB  (K; dead after attn -> FFN chunk scratch)
    //   vb: d_out       bf16 [B,S,D]  32 MiB of the 64 MiB f32 out buffer
    //       (V dead after attn; LN2 then writes f32 over d_out chunk by chunk)
    char* ws = (char*)d_ws;
    bf16* qb = (bf16*)ws;
    bf16* kb = (bf16*)(ws + (32L << 20));
    bf16* vb = (bf16*)d_out;
    bf16* hb = kb;                             // [CHUNK, 4D] bf16 = 16 MiB
    float* yb = (float*)(ws + (48L << 20));    // [CHUNK, D] f32  =  8 MiB

    const dim3 blk(256);

    // QKV projections: [16384,1024] x [1024,1024]^T -> bf16 [B,S,D]
    const dim3 gqkv(D / 64, M_ROWS / 64);
    gemm_kernel<float, bf16, false, false><<<gqkv, blk, 0, stream>>>(src, wq, bq, nullptr, qb, D, D);
    gemm_kernel<float, bf16, false, false><<<gqkv, blk, 0, stream>>>(src, wk, bk, nullptr, kb, D, D);
    gemm_kernel<float, bf16, false, false><<<gqkv, blk, 0, stream>>>(src, wv, bv, nullptr, vb, D, D);

    // Local attention: writes x = 2*attn (bf16) over the Q buffer
    attn_kernel<<<dim3(B * H * NW * 2), blk, 0, stream>>>(qb, kb, vb);

    // LN1 in place: qb now holds x
    ln_kernel<bf16, bf16><<<dim3(M_ROWS), blk, 0, stream>>>(qb, g1, be1, qb);

    // FFN, chunked over rows; scratch lives in the dead K buffer region
    for (int ch = 0; ch < NCH; ++ch) {
        const bf16* xc = qb + (long)ch * CHUNK * D;
        gemm_kernel<bf16, bf16, true, false><<<dim3(4 * D / 64, CHUNK / 64), blk, 0, stream>>>(
            xc, w1, b1, nullptr, hb, D, 4 * D);
        gemm_kernel<bf16, float, false, true><<<dim3(D / 64, CHUNK / 64), blk, 0, stream>>>(
            hb, w2, b2, xc, yb, 4 * D, D);
        ln_kernel<float, float><<<dim3(CHUNK), blk, 0, stream>>>(
            yb, g2, be2, (float*)d_out + (long)ch * CHUNK * D);
    }
}

// Round 4
// 3953.013 us; speedup vs baseline: 2.1297x; 2.1297x over previous
//
#include <hip/hip_runtime.h>
#include <hip/hip_bf16.h>

using bf16 = __hip_bfloat16;
typedef __bf16 bfv8 __attribute__((ext_vector_type(8)));
typedef float f32x4 __attribute__((ext_vector_type(4)));

constexpr int B = 4, S = 4096, D = 1024, H = 16, DH = 64, WIN = 512, NW = S / WIN;
constexpr int M_ROWS = B * S;   // 16384
constexpr int FCH = 2048;       // FFN row chunk (hb = FCH*4096*2 = 16 MiB)
constexpr int NFCH = M_ROWS / FCH;

#define DEV static __device__ __forceinline__

DEV float bf2f(bf16 x) { return __bfloat162float(x); }

DEV void load8_f(const bf16* p, float* dst) {
    const uint4 u = *reinterpret_cast<const uint4*>(p);
    const unsigned w[4] = {u.x, u.y, u.z, u.w};
#pragma unroll
    for (int i = 0; i < 4; ++i) {
        dst[2 * i]     = __uint_as_float(w[i] << 16);
        dst[2 * i + 1] = __uint_as_float(w[i] & 0xffff0000u);
    }
}

DEV unsigned pack2bf(float a, float b) {
    union { __hip_bfloat162 h2; unsigned u; } cv;
    cv.h2.x = __float2bfloat16(a);
    cv.h2.y = __float2bfloat16(b);
    return cv.u;
}

DEV void store_val(float* p, float v) { *p = v; }
DEV void store_val(bf16* p, float v) { *p = __float2bfloat16(v); }

// async global->LDS, 16B per lane; LDS dest = wave-uniform base + lane*16
DEV void gload16(const bf16* g, bf16* l) {
    __builtin_amdgcn_global_load_lds(
        (const __attribute__((address_space(1))) unsigned int*)g,
        (__attribute__((address_space(3))) unsigned int*)l, 16, 0, 0);
}

// ---------------------------------------------------------------------------
// f32 -> bf16 bulk convert (8 elems/thread)
// ---------------------------------------------------------------------------
__global__ __launch_bounds__(256) void f2b_kernel(
    const float* __restrict__ in, bf16* __restrict__ out, int n8) {
    const int i = blockIdx.x * 256 + threadIdx.x;
    if (i >= n8) return;
    const float* p = in + (long)i * 8;
    const float4 a = *(const float4*)p;
    const float4 b = *(const float4*)(p + 4);
    uint4 pk;
    pk.x = pack2bf(a.x, a.y); pk.y = pack2bf(a.z, a.w);
    pk.z = pack2bf(b.x, b.y); pk.w = pack2bf(b.z, b.w);
    *(uint4*)(out + (long)i * 8) = pk;
}

// ---------------------------------------------------------------------------
// MFMA GEMM (m97 structure): out[m,n] = act(sum_k A[m,k]*W[n,k] + bias[n])
// A: [M,K] f32 (convert-on-stage) or bf16 (global_load_lds), W: [N,K] bf16.
// BM = WAVES_M*WM*16, BN = WAVES_N*WN*16, BK=32, 256 threads (4 waves).
// mfma_f32_16x16x32_bf16; A-frag A[m=lane&15][k=quad*8+j]; C/D col=lane&15,
// row=quad*4+reg (verified m89/m91). QKV epilogue splits N in 3x1024 slabs.
// ---------------------------------------------------------------------------
template <typename TA, typename TO, bool RELU, bool RESID, bool QKV,
          int WAVES_M, int WAVES_N, int WM, int WN>
__global__ __launch_bounds__(256) void mfma_gemm(
    const TA* __restrict__ A, const bf16* __restrict__ Wt,
    const float* __restrict__ bias, const bf16* __restrict__ resid,
    TO* __restrict__ out, int K, int N,
    TO* __restrict__ outk, TO* __restrict__ outv,
    const float* __restrict__ biask, const float* __restrict__ biasv) {
    constexpr int BM = WAVES_M * WM * 16;
    constexpr int BN = WAVES_N * WN * 16;
    constexpr int BK = 32;
    __shared__ bf16 As[BM][BK];   // [row][k], row stride 64 B
    __shared__ bf16 Bs[BN][BK];

    const int tid = threadIdx.x;
    const int wid = tid >> 6, lane = tid & 63;
    const int quad = lane >> 4, l16 = lane & 15;
    const int wm = (wid / WAVES_N) * (WM * 16);
    const int wn = (wid % WAVES_N) * (WN * 16);
    const long m0 = (long)blockIdx.y * BM;
    const long n0 = (long)blockIdx.x * BN;
    const int srow = tid >> 2;                // 0..63 (f32 staging row)
    const int sk = (tid & 3) * 8;             // staging k offset (elems)
    const int grow = wid * 16 + (lane >> 2);  // 0..63 (lds-dma staging row)

    f32x4 acc[WM][WN] = {};

    for (int k0 = 0; k0 < K; k0 += BK) {
        __syncthreads();  // prev iteration's LDS reads drained
        if constexpr (sizeof(TA) == 4) {
            // f32 A: VGPR round-trip + convert + ds_write_b128
#pragma unroll
            for (int j = 0; j < BM / 64; ++j) {
                const float* ap = (const float*)A + (m0 + j * 64 + srow) * (long)K + k0 + sk;
                const float4 f0 = *(const float4*)ap;
                const float4 f1 = *(const float4*)(ap + 4);
                uint4 pk;
                pk.x = pack2bf(f0.x, f0.y); pk.y = pack2bf(f0.z, f0.w);
                pk.z = pack2bf(f1.x, f1.y); pk.w = pack2bf(f1.z, f1.w);
                *(uint4*)&As[j * 64 + srow][sk] = pk;
            }
        } else {
#pragma unroll
            for (int j = 0; j < BM / 64; ++j) {
                const bf16* ap = (const bf16*)A + (m0 + j * 64 + grow) * (long)K + k0 + (lane & 3) * 8;
                gload16(ap, (bf16*)((char*)&As[0][0] + j * 4096 + wid * 1024));
            }
        }
#pragma unroll
        for (int j = 0; j < BN / 64; ++j) {
            const bf16* bp = Wt + (n0 + j * 64 + grow) * (long)K + k0 + (lane & 3) * 8;
            gload16(bp, (bf16*)((char*)&Bs[0][0] + j * 4096 + wid * 1024));
        }
        __syncthreads();  // staging visible (incl. lds-dma via vmcnt drain)

        bfv8 af[WM], bfr[WN];
#pragma unroll
        for (int i = 0; i < WM; ++i)
            af[i] = *(const bfv8*)&As[wm + i * 16 + l16][quad * 8];
#pragma unroll
        for (int j = 0; j < WN; ++j)
            bfr[j] = *(const bfv8*)&Bs[wn + j * 16 + l16][quad * 8];
#pragma unroll
        for (int i = 0; i < WM; ++i)
#pragma unroll
            for (int j = 0; j < WN; ++j)
                acc[i][j] = __builtin_amdgcn_mfma_f32_16x16x32_bf16(af[i], bfr[j], acc[i][j], 0, 0, 0);
    }

#pragma unroll
    for (int i = 0; i < WM; ++i) {
#pragma unroll
        for (int r = 0; r < 4; ++r) {
            const long m = m0 + wm + i * 16 + quad * 4 + r;
#pragma unroll
            for (int j = 0; j < WN; ++j) {
                const long n = n0 + wn + j * 16 + l16;
                float val = acc[i][j][r];
                if constexpr (QKV) {
                    // n slab: 0->q, 1->k, 2->v (block-uniform: BN | 1024)
                    const int sel = (int)(n >> 10);
                    const long nn = n & 1023;
                    TO* op = sel == 0 ? out : (sel == 1 ? outk : outv);
                    const float* bp = sel == 0 ? bias : (sel == 1 ? biask : biasv);
                    store_val(op + m * 1024 + nn, val + bp[nn]);
                } else {
                    val += bias[n];
                    if constexpr (RELU) val = fmaxf(val, 0.f);
                    if constexpr (RESID) val += bf2f(resid[m * (long)N + n]);
                    store_val(out + m * (long)N + n, val);
                }
            }
        }
    }
}

// ---------------------------------------------------------------------------
// Local causal attention (verified round 3, unchanged). Q/K/V bf16 [B,S,H*DH].
// One thread/query; fixed-max softmax exp(s-16); x2 folded into 2/l.
// Output overwrites Q in place (each block touches only its own slices).
// ---------------------------------------------------------------------------
__global__ __launch_bounds__(256) void attn_kernel(
    bf16* __restrict__ q, const bf16* __restrict__ k,
    const bf16* __restrict__ v) {
    const int bid = blockIdx.x;
    const int half = bid & 1;
    const int wi = (bid >> 1) & (NW - 1);
    const int bh = bid >> 4;
    const int b_ = bh >> 4, h_ = bh & 15;
    const int qi = half * 256 + threadIdx.x;
    const int qpos = wi * WIN + qi;

    bf16* qrow = q + ((long)b_ * S + qpos) * D + h_ * DH;
    float qf[64];
#pragma unroll
    for (int e8 = 0; e8 < 8; ++e8) load8_f(qrow + e8 * 8, qf + e8 * 8);
#pragma unroll
    for (int e = 0; e < 64; ++e) qf[e] *= 0.125f;

    const int jstart = (wi == 0) ? WIN : 0;
    const int jend = WIN + qi;
    const long kvbase = ((long)b_ * S + (long)(wi - 1) * WIN) * D + h_ * DH;

    float l = 0.f;
    float acc[64] = {};
    for (int j = jstart; j <= jend; ++j) {
        const long off = kvbase + (long)j * D;
        float s = 0.f;
#pragma unroll
        for (int e8 = 0; e8 < 8; ++e8) {
            float kf[8];
            load8_f(k + off + e8 * 8, kf);
#pragma unroll
            for (int i = 0; i < 8; ++i) s = fmaf(qf[e8 * 8 + i], kf[i], s);
        }
        const float p = __expf(s - 16.f);
        l += p;
#pragma unroll
        for (int e8 = 0; e8 < 8; ++e8) {
            float vf[8];
            load8_f(v + off + e8 * 8, vf);
#pragma unroll
            for (int i = 0; i < 8; ++i) acc[e8 * 8 + i] = fmaf(p, vf[i], acc[e8 * 8 + i]);
        }
    }
    const float inv = 2.f / l;
    unsigned pk[32];
#pragma unroll
    for (int e = 0; e < 32; ++e)
        pk[e] = pack2bf(acc[2 * e] * inv, acc[2 * e + 1] * inv);
    uint4* op = reinterpret_cast<uint4*>(qrow);
#pragma unroll
    for (int e4 = 0; e4 < 8; ++e4)
        op[e4] = make_uint4(pk[4 * e4], pk[4 * e4 + 1], pk[4 * e4 + 2], pk[4 * e4 + 3]);
}

// ---------------------------------------------------------------------------
// LayerNorm over last dim (1024), biased var, in-place safe.
// ---------------------------------------------------------------------------
template <typename TI, typename TO>
__global__ __launch_bounds__(256) void ln_kernel(
    const TI* in, const float* __restrict__ g, const float* __restrict__ be,
    TO* out) {
    __shared__ float red[4];
    const long row = blockIdx.x;
    const TI* x = in + row * D;
    const int tid = threadIdx.x;

    float v[4];
    float s = 0.f;
#pragma unroll
    for (int i = 0; i < 4; ++i) {
        v[i] = (float)x[tid + i * 256];
        s += v[i];
    }
#pragma unroll
    for (int off = 32; off; off >>= 1) s += __shfl_down(s, off, 64);
    if ((tid & 63) == 0) red[tid >> 6] = s;
    __syncthreads();
    const float mu = (red[0] + red[1] + red[2] + red[3]) * (1.f / D);
    __syncthreads();

    float vs = 0.f;
#pragma unroll
    for (int i = 0; i < 4; ++i) {
        const float d0 = v[i] - mu;
        vs += d0 * d0;
    }
#pragma unroll
    for (int off = 32; off; off >>= 1) vs += __shfl_down(vs, off, 64);
    if ((tid & 63) == 0) red[tid >> 6] = vs;
    __syncthreads();
    const float inv = rsqrtf((red[0] + red[1] + red[2] + red[3]) * (1.f / D) + 1e-5f);

#pragma unroll
    for (int i = 0; i < 4; ++i) {
        const int c = tid + i * 256;
        store_val(out + row * D + c, (v[i] - mu) * inv * g[c] + be[c]);
    }
}

// ---------------------------------------------------------------------------
extern "C" void kernel_launch(void* const* d_in, const int* in_sizes, int n_in,
                              void* d_out, int out_size, void* d_ws, size_t ws_size,
                              hipStream_t stream) {
    const float* src = (const float*)d_in[0];
    const float* wq = (const float*)d_in[1];  const float* bq = (const float*)d_in[2];
    const float* wk = (const float*)d_in[3];  const float* bk = (const float*)d_in[4];
    const float* wv = (const float*)d_in[5];  const float* bv = (const float*)d_in[6];
    const float* w1 = (const float*)d_in[7];  const float* b1 = (const float*)d_in[8];
    const float* w2 = (const float*)d_in[9];  const float* b2 = (const float*)d_in[10];
    const float* g1 = (const float*)d_in[11]; const float* be1 = (const float*)d_in[12];
    const float* g2 = (const float*)d_in[13]; const float* be2 = (const float*)d_in[14];

    // ws (64 MiB, proven safe):
    //   qb    [ 0,32)  bf16 Q -> 2*attn -> LN1'd x (live through FFN as resid)
    //   w1b   [32,40)  bf16 w1
    //   w2b   [40,48)  bf16 w2
    //   wqkvb [48,54)  bf16 wq|wk|wv   (dead after QKV gemm)
    //   hb    [48,64)  bf16 FFN hidden chunk [2048,4096] (reuses wqkv region)
    // d_out (64 MiB f32):
    //   kb bf16 [0,32), vb bf16 [32,64) -- dead after attn; gemm2 then writes
    //   y f32 over d_out chunk by chunk; LN2 finishes in place.
    char* ws = (char*)d_ws;
    bf16* qb    = (bf16*)ws;
    bf16* w1b   = (bf16*)(ws + (32L << 20));
    bf16* w2b   = (bf16*)(ws + (40L << 20));
    bf16* wqkvb = (bf16*)(ws + (48L << 20));
    bf16* hb    = (bf16*)(ws + (48L << 20));
    bf16* kb    = (bf16*)d_out;
    bf16* vb    = (bf16*)d_out + (16L << 20);  // 32 MiB offset in elems

    const dim3 blk(256);

    // Weight conversions f32 -> bf16
    f2b_kernel<<<dim3(512),  blk, 0, stream>>>(wq, wqkvb,            131072);
    f2b_kernel<<<dim3(512),  blk, 0, stream>>>(wk, wqkvb + (1L<<20), 131072);
    f2b_kernel<<<dim3(512),  blk, 0, stream>>>(wv, wqkvb + (2L<<20), 131072);
    f2b_kernel<<<dim3(2048), blk, 0, stream>>>(w1, w1b,              524288);
    f2b_kernel<<<dim3(2048), blk, 0, stream>>>(w2, w2b,              524288);

    // Fused QKV GEMM: [16384,1024](f32) x [3072,1024]^T -> qb|kb|vb bf16
    mfma_gemm<float, bf16, false, false, true, 2, 2, 4, 4>
        <<<dim3(3072 / 128, M_ROWS / 128), blk, 0, stream>>>(
            src, wqkvb, bq, nullptr, qb, D, 3072, kb, vb, bk, bv);

    // Local attention: x = 2*attn (bf16) over Q buffer
    attn_kernel<<<dim3(B * H * NW * 2), blk, 0, stream>>>(qb, kb, vb);

    // LN1 in place
    ln_kernel<bf16, bf16><<<dim3(M_ROWS), blk, 0, stream>>>(qb, g1, be1, qb);

    // FFN chunks; gemm2 writes f32 y straight into d_out
    for (int ch = 0; ch < NFCH; ++ch) {
        const bf16* xc = qb + (long)ch * FCH * D;
        float* yc = (float*)d_out + (long)ch * FCH * D;
        mfma_gemm<bf16, bf16, true, false, false, 2, 2, 4, 4>
            <<<dim3(4096 / 128, FCH / 128), blk, 0, stream>>>(
                xc, w1b, b1, nullptr, hb, D, 4 * D, nullptr, nullptr, nullptr, nullptr);
        mfma_gemm<bf16, float, false, true, false, 4, 1, 2, 4>
            <<<dim3(1024 / 64, FCH / 128), blk, 0, stream>>>(
                hb, w2b, b2, xc, yc, 4 * D, D, nullptr, nullptr, nullptr, nullptr);
    }

    // LN2 in place on d_out (f32)
    ln_kernel<float, float><<<dim3(M_ROWS), blk, 0, stream>>>(
        (float*)d_out, g2, be2, (float*)d_out);
}

// Round 5
// 1322.532 us; speedup vs baseline: 6.3655x; 2.9890x over previous
//
#include <hip/hip_runtime.h>
#include <hip/hip_bf16.h>

using bf16 = __hip_bfloat16;
typedef __bf16 bfv8 __attribute__((ext_vector_type(8)));
typedef float f32x4 __attribute__((ext_vector_type(4)));

constexpr int B = 4, S = 4096, D = 1024, H = 16, DH = 64, WIN = 512, NW = S / WIN;
constexpr int M_ROWS = B * S;   // 16384
constexpr int FCH = 2048;       // FFN row chunk (hb = FCH*4096*2 = 16 MiB)
constexpr int NFCH = M_ROWS / FCH;

#define DEV static __device__ __forceinline__

DEV float bf2f(bf16 x) { return __bfloat162float(x); }

DEV unsigned pack2bf(float a, float b) {
    union { __hip_bfloat162 h2; unsigned u; } cv;
    cv.h2.x = __float2bfloat16(a);
    cv.h2.y = __float2bfloat16(b);
    return cv.u;
}

DEV void store_val(float* p, float v) { *p = v; }
DEV void store_val(bf16* p, float v) { *p = __float2bfloat16(v); }

// async global->LDS, 16B per lane; LDS dest = wave-uniform base + lane*16
DEV void gload16(const bf16* g, bf16* l) {
    __builtin_amdgcn_global_load_lds(
        (const __attribute__((address_space(1))) unsigned int*)g,
        (__attribute__((address_space(3))) unsigned int*)l, 16, 0, 0);
}

// ---------------------------------------------------------------------------
// f32 -> bf16 bulk convert (8 elems/thread)
// ---------------------------------------------------------------------------
__global__ __launch_bounds__(256) void f2b_kernel(
    const float* __restrict__ in, bf16* __restrict__ out, int n8) {
    const int i = blockIdx.x * 256 + threadIdx.x;
    if (i >= n8) return;
    const float* p = in + (long)i * 8;
    const float4 a = *(const float4*)p;
    const float4 b = *(const float4*)(p + 4);
    uint4 pk;
    pk.x = pack2bf(a.x, a.y); pk.y = pack2bf(a.z, a.w);
    pk.z = pack2bf(b.x, b.y); pk.w = pack2bf(b.z, b.w);
    *(uint4*)(out + (long)i * 8) = pk;
}

// ---------------------------------------------------------------------------
// MFMA GEMM (m97 structure), unchanged from round 3 (verified).
// ---------------------------------------------------------------------------
template <typename TA, typename TO, bool RELU, bool RESID, bool QKV,
          int WAVES_M, int WAVES_N, int WM, int WN>
__global__ __launch_bounds__(256) void mfma_gemm(
    const TA* __restrict__ A, const bf16* __restrict__ Wt,
    const float* __restrict__ bias, const bf16* __restrict__ resid,
    TO* __restrict__ out, int K, int N,
    TO* __restrict__ outk, TO* __restrict__ outv,
    const float* __restrict__ biask, const float* __restrict__ biasv) {
    constexpr int BM = WAVES_M * WM * 16;
    constexpr int BN = WAVES_N * WN * 16;
    constexpr int BK = 32;
    __shared__ bf16 As[BM][BK];
    __shared__ bf16 Bs[BN][BK];

    const int tid = threadIdx.x;
    const int wid = tid >> 6, lane = tid & 63;
    const int quad = lane >> 4, l16 = lane & 15;
    const int wm = (wid / WAVES_N) * (WM * 16);
    const int wn = (wid % WAVES_N) * (WN * 16);
    const long m0 = (long)blockIdx.y * BM;
    const long n0 = (long)blockIdx.x * BN;
    const int srow = tid >> 2;
    const int sk = (tid & 3) * 8;
    const int grow = wid * 16 + (lane >> 2);

    f32x4 acc[WM][WN] = {};

    for (int k0 = 0; k0 < K; k0 += BK) {
        __syncthreads();
        if constexpr (sizeof(TA) == 4) {
#pragma unroll
            for (int j = 0; j < BM / 64; ++j) {
                const float* ap = (const float*)A + (m0 + j * 64 + srow) * (long)K + k0 + sk;
                const float4 f0 = *(const float4*)ap;
                const float4 f1 = *(const float4*)(ap + 4);
                uint4 pk;
                pk.x = pack2bf(f0.x, f0.y); pk.y = pack2bf(f0.z, f0.w);
                pk.z = pack2bf(f1.x, f1.y); pk.w = pack2bf(f1.z, f1.w);
                *(uint4*)&As[j * 64 + srow][sk] = pk;
            }
        } else {
#pragma unroll
            for (int j = 0; j < BM / 64; ++j) {
                const bf16* ap = (const bf16*)A + (m0 + j * 64 + grow) * (long)K + k0 + (lane & 3) * 8;
                gload16(ap, (bf16*)((char*)&As[0][0] + j * 4096 + wid * 1024));
            }
        }
#pragma unroll
        for (int j = 0; j < BN / 64; ++j) {
            const bf16* bp = Wt + (n0 + j * 64 + grow) * (long)K + k0 + (lane & 3) * 8;
            gload16(bp, (bf16*)((char*)&Bs[0][0] + j * 4096 + wid * 1024));
        }
        __syncthreads();

        bfv8 af[WM], bfr[WN];
#pragma unroll
        for (int i = 0; i < WM; ++i)
            af[i] = *(const bfv8*)&As[wm + i * 16 + l16][quad * 8];
#pragma unroll
        for (int j = 0; j < WN; ++j)
            bfr[j] = *(const bfv8*)&Bs[wn + j * 16 + l16][quad * 8];
#pragma unroll
        for (int i = 0; i < WM; ++i)
#pragma unroll
            for (int j = 0; j < WN; ++j)
                acc[i][j] = __builtin_amdgcn_mfma_f32_16x16x32_bf16(af[i], bfr[j], acc[i][j], 0, 0, 0);
    }

#pragma unroll
    for (int i = 0; i < WM; ++i) {
#pragma unroll
        for (int r = 0; r < 4; ++r) {
            const long m = m0 + wm + i * 16 + quad * 4 + r;
#pragma unroll
            for (int j = 0; j < WN; ++j) {
                const long n = n0 + wn + j * 16 + l16;
                float val = acc[i][j][r];
                if constexpr (QKV) {
                    const int sel = (int)(n >> 10);
                    const long nn = n & 1023;
                    TO* op = sel == 0 ? out : (sel == 1 ? outk : outv);
                    const float* bp = sel == 0 ? bias : (sel == 1 ? biask : biasv);
                    store_val(op + m * 1024 + nn, val + bp[nn]);
                } else {
                    val += bias[n];
                    if constexpr (RELU) val = fmaxf(val, 0.f);
                    if constexpr (RESID) val += bf2f(resid[m * (long)N + n]);
                    store_val(out + m * (long)N + n, val);
                }
            }
        }
    }
}

// ---------------------------------------------------------------------------
// MFMA local causal attention. One wg per (b,h,64-query tile); 4 waves of 16
// queries each. Fixed-max softmax p = exp2(s*0.125*log2e - 16*log2e) (scores
// O(+-5): no over/underflow; same math as the verified scalar kernel).
// K staged [key][d] (QK^T B-frag = contiguous b128); V staged transposed
// [d][key] (PV B-frag = contiguous b128); P round-trips LDS per wave
// (C-layout -> A-layout, m120). Rows padded to 72 elems (144 B) -> <=2-way
// bank aliasing (free). Output (2*attn, bf16) overwrites Q in place; each
// wave touches only its own 16 rows x 64 head-cols -> race-free.
// ---------------------------------------------------------------------------
__global__ __launch_bounds__(256) void attn_mfma(
    bf16* __restrict__ q, const bf16* __restrict__ k,
    const bf16* __restrict__ v) {
    constexpr int LDK = 72;
    __shared__ bf16 Ks[64][LDK];
    __shared__ bf16 Vt[64][LDK];
    __shared__ bf16 Ps[4][16][LDK];

    const int tid = threadIdx.x;
    const int wid = tid >> 6, lane = tid & 63;
    const int quad = lane >> 4, l16 = lane & 15;
    const int qt = blockIdx.x & 63;
    const int bh = blockIdx.x >> 6;
    const int b_ = bh >> 4, h_ = bh & 15;
    const int qbase = qt * 64;
    const int wstart = qbase & ~(WIN - 1);
    const int kstart = (wstart == 0) ? 0 : wstart - WIN;
    const int ntiles = (qbase + 64 - kstart) >> 6;

    const long headoff = (long)h_ * DH;

    // Q A-frags: A[m=l16][k=quad*8+j], two k-chunks (0..31, 32..63)
    const bf16* qrow = q + ((long)b_ * S + qbase + wid * 16 + l16) * D + headoff + quad * 8;
    const bfv8 qa0 = *(const bfv8*)qrow;
    const bfv8 qa1 = *(const bfv8*)(qrow + 32);

    // staging index maps
    const int skey = tid >> 2;          // K: row 0..63
    const int sdp  = (tid & 3) * 16;    // K: 16-elem d group
    const int vkey = tid & 63;          // V: key (consecutive lanes -> no conflict)
    const int vdg  = tid >> 6;          // V: d group 0..3

    f32x4 o[4] = {};
    float lacc[4] = {};
    const int qp = qbase + wid * 16 + quad * 4;  // query pos of r=0

    for (int t = 0; t < ntiles; ++t) {
        const int kpos0 = kstart + t * 64;
        __syncthreads();  // prev iteration's LDS reads drained
        {
            const bf16* kp_ = k + ((long)b_ * S + kpos0 + skey) * D + headoff + sdp;
            const uint4 k0 = *(const uint4*)kp_;
            const uint4 k1 = *(const uint4*)(kp_ + 8);
            *(uint4*)&Ks[skey][sdp] = k0;
            *(uint4*)&Ks[skey][sdp + 8] = k1;
            const bf16* vp_ = v + ((long)b_ * S + kpos0 + vkey) * D + headoff + vdg * 16;
            bf16 vv[16];
            *(uint4*)&vv[0] = *(const uint4*)vp_;
            *(uint4*)&vv[8] = *(const uint4*)(vp_ + 8);
#pragma unroll
            for (int i = 0; i < 16; ++i) Vt[vdg * 16 + i][vkey] = vv[i];
        }
        __syncthreads();

        // S = Q K^T  (4 chunks of 16 keys), then p = exp2(fma(s)) masked
#pragma unroll
        for (int c = 0; c < 4; ++c) {
            const bfv8 kb0 = *(const bfv8*)&Ks[c * 16 + l16][quad * 8];
            const bfv8 kb1 = *(const bfv8*)&Ks[c * 16 + l16][quad * 8 + 32];
            f32x4 s = {};
            s = __builtin_amdgcn_mfma_f32_16x16x32_bf16(qa0, kb0, s, 0, 0, 0);
            s = __builtin_amdgcn_mfma_f32_16x16x32_bf16(qa1, kb1, s, 0, 0, 0);
            const int kp = kpos0 + c * 16 + l16;
#pragma unroll
            for (int r = 0; r < 4; ++r) {
                const float p = (kp <= qp + r)
                    ? exp2f(fmaf(s[r], 0.18033688f, -23.083120f)) : 0.f;
                lacc[r] += p;
                Ps[wid][quad * 4 + r][c * 16 + l16] = __float2bfloat16(p);
            }
        }

        // O += P V   (A from Ps round-trip, B from transposed Vt)
#pragma unroll
        for (int c2 = 0; c2 < 2; ++c2) {
            const bfv8 pa = *(const bfv8*)&Ps[wid][l16][c2 * 32 + quad * 8];
#pragma unroll
            for (int dc = 0; dc < 4; ++dc) {
                const bfv8 vb = *(const bfv8*)&Vt[dc * 16 + l16][c2 * 32 + quad * 8];
                o[dc] = __builtin_amdgcn_mfma_f32_16x16x32_bf16(pa, vb, o[dc], 0, 0, 0);
            }
        }
    }

    // reduce l across the 16-lane key-column group (masks 1,2,4,8 stay in-group)
#pragma unroll
    for (int r = 0; r < 4; ++r) {
#pragma unroll
        for (int m = 1; m < 16; m <<= 1) lacc[r] += __shfl_xor(lacc[r], m, 64);
    }
    float inv[4];
#pragma unroll
    for (int r = 0; r < 4; ++r) inv[r] = 2.f / lacc[r];  // x2 = "attn + attn"

    bf16* orow = q + ((long)b_ * S + qp) * D + headoff;
#pragma unroll
    for (int r = 0; r < 4; ++r)
#pragma unroll
        for (int dc = 0; dc < 4; ++dc)
            orow[(long)r * D + dc * 16 + l16] = __float2bfloat16(o[dc][r] * inv[r]);
}

// ---------------------------------------------------------------------------
// LayerNorm over last dim (1024), biased var, in-place safe.
// ---------------------------------------------------------------------------
template <typename TI, typename TO>
__global__ __launch_bounds__(256) void ln_kernel(
    const TI* in, const float* __restrict__ g, const float* __restrict__ be,
    TO* out) {
    __shared__ float red[4];
    const long row = blockIdx.x;
    const TI* x = in + row * D;
    const int tid = threadIdx.x;

    float v[4];
    float s = 0.f;
#pragma unroll
    for (int i = 0; i < 4; ++i) {
        v[i] = (float)x[tid + i * 256];
        s += v[i];
    }
#pragma unroll
    for (int off = 32; off; off >>= 1) s += __shfl_down(s, off, 64);
    if ((tid & 63) == 0) red[tid >> 6] = s;
    __syncthreads();
    const float mu = (red[0] + red[1] + red[2] + red[3]) * (1.f / D);
    __syncthreads();

    float vs = 0.f;
#pragma unroll
    for (int i = 0; i < 4; ++i) {
        const float d0 = v[i] - mu;
        vs += d0 * d0;
    }
#pragma unroll
    for (int off = 32; off; off >>= 1) vs += __shfl_down(vs, off, 64);
    if ((tid & 63) == 0) red[tid >> 6] = vs;
    __syncthreads();
    const float inv = rsqrtf((red[0] + red[1] + red[2] + red[3]) * (1.f / D) + 1e-5f);

#pragma unroll
    for (int i = 0; i < 4; ++i) {
        const int c = tid + i * 256;
        store_val(out + row * D + c, (v[i] - mu) * inv * g[c] + be[c]);
    }
}

// ---------------------------------------------------------------------------
extern "C" void kernel_launch(void* const* d_in, const int* in_sizes, int n_in,
                              void* d_out, int out_size, void* d_ws, size_t ws_size,
                              hipStream_t stream) {
    const float* src = (const float*)d_in[0];
    const float* wq = (const float*)d_in[1];  const float* bq = (const float*)d_in[2];
    const float* wk = (const float*)d_in[3];  const float* bk = (const float*)d_in[4];
    const float* wv = (const float*)d_in[5];  const float* bv = (const float*)d_in[6];
    const float* w1 = (const float*)d_in[7];  const float* b1 = (const float*)d_in[8];
    const float* w2 = (const float*)d_in[9];  const float* b2 = (const float*)d_in[10];
    const float* g1 = (const float*)d_in[11]; const float* be1 = (const float*)d_in[12];
    const float* g2 = (const float*)d_in[13]; const float* be2 = (const float*)d_in[14];

    // ws (64 MiB):  qb[0,32) | w1b[32,40) | w2b[40,48) | wqkvb[48,54)->hb[48,64)
    // d_out (64 MiB f32): kb bf16 [0,32), vb bf16 [32,64) during attention;
    // then FFN2 writes f32 y over it chunk by chunk; LN2 in place.
    char* ws = (char*)d_ws;
    bf16* qb    = (bf16*)ws;
    bf16* w1b   = (bf16*)(ws + (32L << 20));
    bf16* w2b   = (bf16*)(ws + (40L << 20));
    bf16* wqkvb = (bf16*)(ws + (48L << 20));
    bf16* hb    = (bf16*)(ws + (48L << 20));
    bf16* kb    = (bf16*)d_out;
    bf16* vb    = (bf16*)d_out + (16L << 20);

    const dim3 blk(256);

    f2b_kernel<<<dim3(512),  blk, 0, stream>>>(wq, wqkvb,            131072);
    f2b_kernel<<<dim3(512),  blk, 0, stream>>>(wk, wqkvb + (1L<<20), 131072);
    f2b_kernel<<<dim3(512),  blk, 0, stream>>>(wv, wqkvb + (2L<<20), 131072);
    f2b_kernel<<<dim3(2048), blk, 0, stream>>>(w1, w1b,              524288);
    f2b_kernel<<<dim3(2048), blk, 0, stream>>>(w2, w2b,              524288);

    // Fused QKV GEMM: [16384,1024](f32) x [3072,1024]^T -> qb|kb|vb bf16
    mfma_gemm<float, bf16, false, false, true, 2, 2, 4, 4>
        <<<dim3(3072 / 128, M_ROWS / 128), blk, 0, stream>>>(
            src, wqkvb, bq, nullptr, qb, D, 3072, kb, vb, bk, bv);

    // MFMA local attention: x = 2*attn (bf16) over Q buffer
    attn_mfma<<<dim3(B * H * (S / 64)), blk, 0, stream>>>(qb, kb, vb);

    // LN1 in place
    ln_kernel<bf16, bf16><<<dim3(M_ROWS), blk, 0, stream>>>(qb, g1, be1, qb);

    // FFN chunks; gemm2 writes f32 y straight into d_out
    for (int ch = 0; ch < NFCH; ++ch) {
        const bf16* xc = qb + (long)ch * FCH * D;
        float* yc = (float*)d_out + (long)ch * FCH * D;
        mfma_gemm<bf16, bf16, true, false, false, 2, 2, 4, 4>
            <<<dim3(4096 / 128, FCH / 128), blk, 0, stream>>>(
                xc, w1b, b1, nullptr, hb, D, 4 * D, nullptr, nullptr, nullptr, nullptr);
        mfma_gemm<bf16, float, false, true, false, 4, 1, 2, 4>
            <<<dim3(1024 / 64, FCH / 128), blk, 0, stream>>>(
                hb, w2b, b2, xc, yc, 4 * D, D, nullptr, nullptr, nullptr, nullptr);
    }

    // LN2 in place on d_out (f32)
    ln_kernel<float, float><<<dim3(M_ROWS), blk, 0, stream>>>(
        (float*)d_out, g2, be2, (float*)d_out);
}